// Round 2
// baseline (237.700 us; speedup 1.0000x reference)
//
#include <hip/hip_runtime.h>
#include <math.h>

#define B_ 2
#define C_ 32
#define D_ 32
#define H_ 32
#define W_ 64
#define HW_ (H_*W_)         // 2048
#define DHW_ (D_*H_*W_)     // 65536
#define CDHW_ (C_*DHW_)     // 2097152
#define NSP_ DHW_           // spatial points per batch
#define BN_N_ (B_*DHW_)     // 131072
#define ACC_OFF 16777216    // byte offset of double accumulators in ws (after M)
#define BORDER 1e-3

#define TW 16               // w-tile width (floats) for staged pass kernels
#define RS 20               // padded LDS row stride: 16 + 4 keeps 16B alignment, spreads banks
#define TC 8                // channels per chunk

// acc double layout: [0..1] norm_sum[b], [2..3] norm_sumsq[b], [4..35] bn_sum[o], [36..67] bn_sumsq[o]

// ---------------- threshold stats: norm = sum_c |x - roll(x, half)| ----------------
__global__ __launch_bounds__(256) void k_norm(const float* __restrict__ x, double* __restrict__ acc) {
    int idx = blockIdx.x * 256 + threadIdx.x;          // 0..131071
    int b = idx >> 16;
    int p = idx & 65535;
    int d = p >> 11, h = (p >> 6) & 31, w = p & 63;
    int pf = ((d ^ 16) << 11) | ((h ^ 16) << 6) | (w ^ 32);   // (i - n/2) mod n == i ^ (n/2)
    const float* xb = x + (size_t)b * CDHW_;
    double s = 0.0;
#pragma unroll
    for (int c = 0; c < 32; ++c) {
        float a  = xb[c * DHW_ + p];
        float bb = xb[c * DHW_ + pf];
        s += fabs((double)a - (double)bb);
    }
    double s2 = s * s;
    for (int off = 32; off; off >>= 1) {
        s  += __shfl_down(s,  off, 64);
        s2 += __shfl_down(s2, off, 64);
    }
    __shared__ double ls[4], ls2[4];
    int wv = threadIdx.x >> 6, ln = threadIdx.x & 63;
    if (ln == 0) { ls[wv] = s; ls2[wv] = s2; }
    __syncthreads();
    if (threadIdx.x == 0) {
        double t  = ls[0] + ls[1] + ls[2] + ls[3];
        double t2 = ls2[0] + ls2[1] + ls2[2] + ls2[3];
        atomicAdd(&acc[0 + b], t);
        atomicAdd(&acc[2 + b], t2);
    }
}

__device__ __forceinline__ double get_thr(const double* __restrict__ acc, int b) {
    double sum = acc[b], sq = acc[2 + b];
    double n = (double)NSP_;
    double mean = sum / n;
    double var = (sq - sum * sum / n) / (n - 1.0);   // ddof=1
    if (var < 0.0) var = 0.0;
    return mean - sqrt(var);
}

// ---------------- axis pass along W: one wave per (b,d,h) line, lane = w (coalesced) ----------------
__global__ __launch_bounds__(256) void k_pass_w(const float* __restrict__ x, const double* __restrict__ acc,
                                                float* __restrict__ M) {
    int wv = blockIdx.x * 4 + (threadIdx.x >> 6);   // 0..2047 lines
    int ln = threadIdx.x & 63;
    int b = wv >> 10, d = (wv >> 5) & 31, h = wv & 31;
    double thr = get_thr(acc, b);
    const float* base = x + (size_t)b * CDHW_ + d * HW_ + h * W_ + ln;
    float col[32], nb[32], Mv[32];
#pragma unroll
    for (int c = 0; c < 32; ++c) col[c] = base[c * DHW_];
#pragma unroll
    for (int c = 0; c < 32; ++c) { nb[c] = col[c]; Mv[c] = col[c]; }   // s=0/unselected => 0 after relu
    int src = (ln - 2) & 63;
    for (int si = 1; si < 32; ++si) {               // shift s = 2*si
#pragma unroll
        for (int c = 0; c < 32; ++c) nb[c] = __shfl(nb[c], src, 64);   // nb = x[w - 2*si]
        float d0 = 0.f, d1 = 0.f, d2 = 0.f, d3 = 0.f;
#pragma unroll
        for (int c = 0; c < 32; c += 4) {
            d0 += fabsf(col[c+0] - nb[c+0]);
            d1 += fabsf(col[c+1] - nb[c+1]);
            d2 += fabsf(col[c+2] - nb[c+2]);
            d3 += fabsf(col[c+3] - nb[c+3]);
        }
        float ds = (d0 + d1) + (d2 + d3);
        bool cmp;
        bool border = fabs((double)ds - thr) < BORDER;
        if (__ballot(border)) {                     // rare exact path, wave-uniform branch
            double d64 = 0.0;
#pragma unroll
            for (int c = 0; c < 32; ++c) d64 += fabs((double)col[c] - (double)nb[c]);
            cmp = d64 < thr;
        } else {
            cmp = ((double)ds < thr);
        }
#pragma unroll
        for (int c = 0; c < 32; ++c) Mv[c] = (cmp && nb[c] > Mv[c]) ? nb[c] : Mv[c];
    }
    float* mb = M + (size_t)b * CDHW_ + d * HW_ + h * W_ + ln;
#pragma unroll
    for (int c = 0; c < 32; ++c) mb[c * DHW_] = Mv[c];
}

// ---------------- LDS-staged axis pass (H or D). AXS = stride along pass axis,
// OTS = stride of the fixed other axis. One block per (b, fix, w-tile of 16).
// 512 threads = 8 waves; lane = pos*2 + wsub covers 32 positions x 2 w; wave wv covers w-pair 2wv,2wv+1.
template<int AXS, int OTS>
__global__ __launch_bounds__(512) void k_pass_t(const float* __restrict__ x, const double* __restrict__ acc,
                                                float* __restrict__ M) {
    __shared__ __align__(16) float tile[TC * 32 * RS];   // 20 KB
    int t = threadIdx.x;
    int wt = blockIdx.x, fix = blockIdx.y, b = blockIdx.z;
    int w0 = wt * TW;
    int ln = t & 63, wv = t >> 6;
    int pos = ln >> 1;                  // position along pass axis (0..31)
    int wloc = wv * 2 + (ln & 1);       // 0..15 within w-tile
    double thr = get_thr(acc, b);
    const float* xb = x + (size_t)b * CDHW_ + (size_t)fix * OTS + w0;
    int src = (ln - 4) & 63;            // rotate by 2 along axis

    float dist[16];
#pragma unroll
    for (int i = 0; i < 16; ++i) dist[i] = 0.f;

    // ---- phase 1: accumulate dist[s] over channel chunks
    for (int cc = 0; cc < 4; ++cc) {
        int c0 = cc * TC;
#pragma unroll
        for (int i = 0; i < 2; ++i) {
            int f = t + i * 512;                         // 0..1023 float4s
            int c = f >> 7, rem = f & 127, pp = rem >> 2, q = rem & 3;
            float4 v = *(const float4*)(xb + (size_t)(c0 + c) * DHW_ + (size_t)pp * AXS + q * 4);
            *(float4*)(&tile[c * (32 * RS) + pp * RS + q * 4]) = v;
        }
        __syncthreads();
        float col[TC], nb[TC];
#pragma unroll
        for (int c = 0; c < TC; ++c) { col[c] = tile[c * (32 * RS) + pos * RS + wloc]; nb[c] = col[c]; }
        __syncthreads();
#pragma unroll
        for (int si = 1; si < 16; ++si) {
#pragma unroll
            for (int c = 0; c < TC; ++c) nb[c] = __shfl(nb[c], src, 64);
            float s0 = 0.f, s1 = 0.f;
#pragma unroll
            for (int c = 0; c < TC; c += 2) {
                s0 += fabsf(col[c]     - nb[c]);
                s1 += fabsf(col[c + 1] - nb[c + 1]);
            }
            dist[si] += s0 + s1;
        }
    }

    // ---- masks (fp64 border fallback reads global directly; rare, wave-uniform)
    unsigned mask = 0, bflag = 0;
#pragma unroll
    for (int si = 1; si < 16; ++si) {
        double dd = (double)dist[si];
        if (fabs(dd - thr) < BORDER) bflag |= 1u << si;
        if (dd < thr) mask |= 1u << si;
    }
    if (__ballot(bflag != 0)) {
        const float* xp = xb + wloc;
        for (int si = 1; si < 16; ++si) {
            if (__ballot((bflag >> si) & 1)) {
                int p2 = (pos - 2 * si) & 31;
                double d64 = 0.0;
                for (int c = 0; c < 32; ++c) {
                    double a  = xp[(size_t)c * DHW_ + (size_t)pos * AXS];
                    double b2 = xp[(size_t)c * DHW_ + (size_t)p2  * AXS];
                    d64 += fabs(a - b2);
                }
                mask = (mask & ~(1u << si)) | ((unsigned)(d64 < thr) << si);
            }
        }
    }

    // ---- phase 2: apply mask, merge into M (coalesced float4 r/m/w)
    float* Mb = M + (size_t)b * CDHW_ + (size_t)fix * OTS + w0;
    for (int cc = 0; cc < 4; ++cc) {
        int c0 = cc * TC;
#pragma unroll
        for (int i = 0; i < 2; ++i) {
            int f = t + i * 512;
            int c = f >> 7, rem = f & 127, pp = rem >> 2, q = rem & 3;
            float4 v = *(const float4*)(xb + (size_t)(c0 + c) * DHW_ + (size_t)pp * AXS + q * 4);
            *(float4*)(&tile[c * (32 * RS) + pp * RS + q * 4]) = v;
        }
        __syncthreads();
        float col[TC], nb[TC], Mv[TC];
#pragma unroll
        for (int c = 0; c < TC; ++c) {
            col[c] = tile[c * (32 * RS) + pos * RS + wloc];
            nb[c] = col[c]; Mv[c] = col[c];
        }
        __syncthreads();
#pragma unroll
        for (int si = 1; si < 16; ++si) {
#pragma unroll
            for (int c = 0; c < TC; ++c) nb[c] = __shfl(nb[c], src, 64);
            bool cm = (mask >> si) & 1;
#pragma unroll
            for (int c = 0; c < TC; ++c) Mv[c] = (cm && nb[c] > Mv[c]) ? nb[c] : Mv[c];
        }
#pragma unroll
        for (int c = 0; c < TC; ++c) tile[c * (32 * RS) + pos * RS + wloc] = Mv[c];
        __syncthreads();
#pragma unroll
        for (int i = 0; i < 2; ++i) {
            int f = t + i * 512;
            int c = f >> 7, rem = f & 127, pp = rem >> 2, q = rem & 3;
            float* gp = Mb + (size_t)(c0 + c) * DHW_ + (size_t)pp * AXS + q * 4;
            float4 mv = *(float4*)(&tile[c * (32 * RS) + pp * RS + q * 4]);
            float4 old = *(const float4*)gp;
            mv.x = fmaxf(mv.x, old.x); mv.y = fmaxf(mv.y, old.y);
            mv.z = fmaxf(mv.z, old.z); mv.w = fmaxf(mv.w, old.w);
            *(float4*)gp = mv;
        }
        __syncthreads();
    }
}

// ---------------- 1x1x1 conv (64 -> 32) + per-channel batch stats ----------------
__global__ __launch_bounds__(256) void k_conv(const float* __restrict__ x, const float* __restrict__ M,
                                              const float* __restrict__ w, const float* __restrict__ bias,
                                              float* __restrict__ y, double* __restrict__ acc) {
    int idx = blockIdx.x * 256 + threadIdx.x;       // 0..131071 spatial points
    int b = idx >> 16, p = idx & 65535;
    const float* xb = x + (size_t)b * CDHW_ + p;
    const float* mb = M + (size_t)b * CDHW_ + p;
    float z[64];
#pragma unroll
    for (int c = 0; c < 32; ++c) {
        float xv = xb[c * DHW_];
        z[c] = xv;
        float xj = mb[c * DHW_] - xv;               // M >= x always; relu still applied for safety
        z[32 + c] = xj > 0.f ? xj : 0.f;
    }
    __shared__ float ytile[256][33];
    float* yout = y + (size_t)b * CDHW_ + p;        // [b][o][p], OC==C
    for (int o = 0; o < 32; ++o) {
        float a = bias[o];
#pragma unroll
        for (int c = 0; c < 64; ++c) a = fmaf(w[o * 64 + c], z[c], a);
        yout[o * DHW_] = a;
        ytile[threadIdx.x][o] = a;
    }
    __syncthreads();
    int o = threadIdx.x & 31, seg = threadIdx.x >> 5;
    float ps = 0.f, pq = 0.f;
#pragma unroll
    for (int j = 0; j < 32; ++j) {
        float v = ytile[seg * 32 + j][o];
        ps += v; pq += v * v;
    }
    __shared__ float psum[8][32], psq[8][32];
    psum[seg][o] = ps; psq[seg][o] = pq;
    __syncthreads();
    if (threadIdx.x < 32) {
        double ts = 0.0, tq = 0.0;
#pragma unroll
        for (int s2 = 0; s2 < 8; ++s2) { ts += (double)psum[s2][threadIdx.x]; tq += (double)psq[s2][threadIdx.x]; }
        atomicAdd(&acc[4 + threadIdx.x], ts);
        atomicAdd(&acc[36 + threadIdx.x], tq);
    }
}

// ---------------- BN normalize (training stats, biased var) + exact GELU, in-place ----------------
__global__ __launch_bounds__(256) void k_out(float* __restrict__ y, const double* __restrict__ acc,
                                             const float* __restrict__ gamma, const float* __restrict__ beta) {
    int idx = blockIdx.x * 256 + threadIdx.x;       // over 1,048,576 float4
    int elem = idx << 2;
    int o = (elem >> 16) & 31;
    double mu = acc[4 + o] / (double)BN_N_;
    double var = acc[36 + o] / (double)BN_N_ - mu * mu;
    float rstd = (float)(1.0 / sqrt(var + 1e-5));
    float mu_f = (float)mu;
    float g = gamma[o], be = beta[o];
    float4 v = ((const float4*)y)[idx];
    float* vv = (float*)&v;
#pragma unroll
    for (int j = 0; j < 4; ++j) {
        float t = (vv[j] - mu_f) * rstd * g + be;
        vv[j] = 0.5f * t * (1.f + erff(t * 0.70710678118654752f));
    }
    ((float4*)y)[idx] = v;
}

extern "C" void kernel_launch(void* const* d_in, const int* in_sizes, int n_in,
                              void* d_out, int out_size, void* d_ws, size_t ws_size,
                              hipStream_t stream) {
    const float* x     = (const float*)d_in[0];
    const float* w     = (const float*)d_in[1];
    const float* bias  = (const float*)d_in[2];
    const float* gamma = (const float*)d_in[3];
    const float* beta  = (const float*)d_in[4];
    float* out = (float*)d_out;
    float* M   = (float*)d_ws;
    double* acc = (double*)((char*)d_ws + ACC_OFF);

    hipMemsetAsync(acc, 0, 68 * sizeof(double), stream);     // zero f64 accumulators every call
    k_norm  <<<512, 256, 0, stream>>>(x, acc);
    k_pass_w<<<512, 256, 0, stream>>>(x, acc, M);
    k_pass_t<W_,  HW_><<<dim3(4, 32, 2), 512, 0, stream>>>(x, acc, M);   // H pass (fix = d)
    k_pass_t<HW_, W_ ><<<dim3(4, 32, 2), 512, 0, stream>>>(x, acc, M);   // D pass (fix = h)
    k_conv  <<<512, 256, 0, stream>>>(x, M, w, bias, out, acc);
    k_out   <<<4096, 256, 0, stream>>>(out, acc, gamma, beta);
}

// Round 3
// 166.419 us; speedup vs baseline: 1.4283x; 1.4283x over previous
//
#include <hip/hip_runtime.h>
#include <math.h>

#define B_ 2
#define C_ 32
#define D_ 32
#define H_ 32
#define W_ 64
#define HW_ (H_*W_)         // 2048
#define DHW_ (D_*H_*W_)     // 65536
#define CDHW_ (C_*DHW_)     // 2097152
#define NSP_ DHW_           // spatial points per batch
#define BN_N_ (B_*DHW_)     // 131072
#define ACC_OFF 16777216    // byte offset of double accumulators in ws (after MT)
#define BORDER 1e-3

// ws layout: MT transposed [b][p][c] (16 MB), then 68 doubles of accumulators.
// acc: [0..1] norm_sum[b], [2..3] norm_sumsq[b], [4..35] bn_sum[o], [36..67] bn_sumsq[o]

// ---------------- threshold stats: norm = sum_c |x - roll(x, half)| ----------------
__global__ __launch_bounds__(256) void k_norm(const float* __restrict__ x, double* __restrict__ acc) {
    int idx = blockIdx.x * 256 + threadIdx.x;          // 0..131071
    int b = idx >> 16;
    int p = idx & 65535;
    int d = p >> 11, h = (p >> 6) & 31, w = p & 63;
    int pf = ((d ^ 16) << 11) | ((h ^ 16) << 6) | (w ^ 32);   // (i - n/2) mod n == i ^ (n/2)
    const float* xb = x + (size_t)b * CDHW_;
    double s = 0.0;
#pragma unroll
    for (int c = 0; c < 32; ++c) {
        float a  = xb[c * DHW_ + p];
        float bb = xb[c * DHW_ + pf];
        s += fabs((double)a - (double)bb);
    }
    double s2 = s * s;
    for (int off = 32; off; off >>= 1) {
        s  += __shfl_down(s,  off, 64);
        s2 += __shfl_down(s2, off, 64);
    }
    __shared__ double ls[4], ls2[4];
    int wv = threadIdx.x >> 6, ln = threadIdx.x & 63;
    if (ln == 0) { ls[wv] = s; ls2[wv] = s2; }
    __syncthreads();
    if (threadIdx.x == 0) {
        double t  = ls[0] + ls[1] + ls[2] + ls[3];
        double t2 = ls2[0] + ls2[1] + ls2[2] + ls2[3];
        atomicAdd(&acc[0 + b], t);
        atomicAdd(&acc[2 + b], t2);
    }
}

__device__ __forceinline__ double get_thr(const double* __restrict__ acc, int b) {
    double sum = acc[b], sq = acc[2 + b];
    double n = (double)NSP_;
    double mean = sum / n;
    double var = (sq - sum * sum / n) / (n - 1.0);   // ddof=1
    if (var < 0.0) var = 0.0;
    return mean - sqrt(var);
}

__device__ __forceinline__ float dist32(const float* col, const float* nb) {
    float d0 = 0.f, d1 = 0.f, d2 = 0.f, d3 = 0.f;
#pragma unroll
    for (int c = 0; c < 32; c += 4) {
        d0 += fabsf(col[c+0] - nb[c+0]);
        d1 += fabsf(col[c+1] - nb[c+1]);
        d2 += fabsf(col[c+2] - nb[c+2]);
        d3 += fabsf(col[c+3] - nb[c+3]);
    }
    return (d0 + d1) + (d2 + d3);
}

// cmp with rare fp64 fallback (wave-uniform branch), data in registers
__device__ __forceinline__ bool gate(float ds, double thr, const float* col, const float* nb) {
    bool border = fabs((double)ds - thr) < BORDER;
    if (__ballot(border)) {
        double d64 = 0.0;
#pragma unroll
        for (int c = 0; c < 32; ++c) d64 += fabs((double)col[c] - (double)nb[c]);
        return d64 < thr;
    }
    return (double)ds < thr;
}

// ---------------- axis pass along W: one wave per (b,d,h) line, lane = w ----------------
// independent shuffles from col (no chain); pair symmetry: decision for reverse shift
// (32-s) is the forward decision shuffled from the partner lane.
__global__ __launch_bounds__(256) void k_pass_w(const float* __restrict__ x, const double* __restrict__ acc,
                                                float* __restrict__ MT) {
    int wvg = blockIdx.x * 4 + (threadIdx.x >> 6);   // 0..2047 lines
    int ln = threadIdx.x & 63;
    int b = wvg >> 10, d = (wvg >> 5) & 31, h = wvg & 31;
    double thr = get_thr(acc, b);
    const float* base = x + (size_t)b * CDHW_ + d * HW_ + h * W_ + ln;
    float col[32], Mv[32], nb[32];
#pragma unroll
    for (int c = 0; c < 32; ++c) { col[c] = base[c * DHW_]; Mv[c] = col[c]; }
    for (int si = 1; si <= 15; ++si) {
        int srcf = (ln - 2 * si) & 63;
        int srcr = (ln + 2 * si) & 63;
#pragma unroll
        for (int c = 0; c < 32; ++c) nb[c] = __shfl(col[c], srcf, 64);
        float ds = dist32(col, nb);
        bool cmp = gate(ds, thr, col, nb);
#pragma unroll
        for (int c = 0; c < 32; ++c) Mv[c] = (cmp && nb[c] > Mv[c]) ? nb[c] : Mv[c];
        int cr = __shfl(cmp ? 1 : 0, srcr, 64);      // partner's decision == ours for pair (i, i+2si)
#pragma unroll
        for (int c = 0; c < 32; ++c) nb[c] = __shfl(col[c], srcr, 64);
        bool cmpr = (cr != 0);
#pragma unroll
        for (int c = 0; c < 32; ++c) Mv[c] = (cmpr && nb[c] > Mv[c]) ? nb[c] : Mv[c];
    }
    {   // s = 16 (w-shift 32): self-paired
#pragma unroll
        for (int c = 0; c < 32; ++c) nb[c] = __shfl(col[c], ln ^ 32, 64);
        float ds = dist32(col, nb);
        bool cmp = gate(ds, thr, col, nb);
#pragma unroll
        for (int c = 0; c < 32; ++c) Mv[c] = (cmp && nb[c] > Mv[c]) ? nb[c] : Mv[c];
    }
    float* mp = MT + ((size_t)b * 65536 + (size_t)d * HW_ + h * W_ + ln) * 32;
#pragma unroll
    for (int q = 0; q < 8; ++q) {
        float4 v; v.x = Mv[4*q]; v.y = Mv[4*q+1]; v.z = Mv[4*q+2]; v.w = Mv[4*q+3];
        *(float4*)(mp + 4 * q) = v;
    }
}

// ---------------- LDS-staged ring pass for H/D axes ----------------
// AS = point stride along pass axis, FS = point stride of the fixed coord.
// Block: 16 rings of 16 positions (fixed F, 8 consecutive w, 2 parities), all 32 channels.
// LDS layout: ring*512 + pos*32 + ((q ^ (pos&7))<<2) + (c&3)  (XOR quad swizzle, bank-floor b128)
template<int AS, int FS>
__global__ __launch_bounds__(256) void k_ring16(const float* __restrict__ x, const double* __restrict__ acc,
                                                float* __restrict__ MT) {
    __shared__ __align__(16) float L[8192];          // 32 KB
    int t = threadIdx.x;
    int w0 = blockIdx.x * 8;
    int F = blockIdx.y;
    int b = blockIdx.z;
    double thr = get_thr(acc, b);
    const float* xb = x + (size_t)b * CDHW_ + (size_t)F * FS + w0;
#pragma unroll
    for (int it = 0; it < 8; ++it) {
        int f = it * 256 + t;                        // 0..2047 float4s
        int a = f >> 6, c = (f >> 1) & 31, wq = f & 1;
        float4 v = *(const float4*)(xb + (size_t)c * DHW_ + (size_t)a * AS + wq * 4);
        int j = a >> 1, par = a & 1;
        int sl = (((c >> 2) ^ (j & 7)) << 2) + (c & 3);
        int rb = (par * 8 + wq * 4) * 512 + j * 32 + sl;
        L[rb] = v.x; L[rb + 512] = v.y; L[rb + 1024] = v.z; L[rb + 1536] = v.w;
    }
    __syncthreads();
    int ln = t & 63, wv = t >> 6;
    int rl = ln >> 4, i = ln & 15;
    int ring = wv * 4 + rl;
    const float* Lr = L + ring * 512;
    float col[32], Mv[32], nb[32];
#pragma unroll
    for (int q = 0; q < 8; ++q) {
        float4 cv = *(const float4*)(Lr + i * 32 + ((q ^ (i & 7)) << 2));
        col[4*q] = cv.x; col[4*q+1] = cv.y; col[4*q+2] = cv.z; col[4*q+3] = cv.w;
    }
#pragma unroll
    for (int c = 0; c < 32; ++c) Mv[c] = col[c];
    for (int s = 1; s < 16; ++s) {
        int jj = (i - s) & 15;
#pragma unroll
        for (int q = 0; q < 8; ++q) {
            float4 nv = *(const float4*)(Lr + jj * 32 + ((q ^ (jj & 7)) << 2));
            nb[4*q] = nv.x; nb[4*q+1] = nv.y; nb[4*q+2] = nv.z; nb[4*q+3] = nv.w;
        }
        float ds = dist32(col, nb);
        bool cmp = gate(ds, thr, col, nb);
#pragma unroll
        for (int c = 0; c < 32; ++c) Mv[c] = (cmp && nb[c] > Mv[c]) ? nb[c] : Mv[c];
    }
    int par = ring >> 3, wl = ring & 7;
    size_t p = (size_t)F * FS + (size_t)(2 * i + par) * AS + w0 + wl;
    float* mp = MT + ((size_t)b * 65536 + p) * 32;
#pragma unroll
    for (int q = 0; q < 8; ++q) {
        float4 old = *(const float4*)(mp + 4 * q);
        old.x = fmaxf(old.x, Mv[4*q]);   old.y = fmaxf(old.y, Mv[4*q+1]);
        old.z = fmaxf(old.z, Mv[4*q+2]); old.w = fmaxf(old.w, Mv[4*q+3]);
        *(float4*)(mp + 4 * q) = old;
    }
}

// ---------------- 1x1x1 conv (64 -> 32) + per-channel batch stats ----------------
__global__ __launch_bounds__(256) void k_conv(const float* __restrict__ x, const float* __restrict__ MT,
                                              const float* __restrict__ w, const float* __restrict__ bias,
                                              float* __restrict__ y, double* __restrict__ acc) {
    int idx = blockIdx.x * 256 + threadIdx.x;       // 0..131071 spatial points
    int b = idx >> 16, p = idx & 65535;
    const float* xb = x + (size_t)b * CDHW_ + p;
    const float4* mt = (const float4*)(MT + ((size_t)b * 65536 + p) * 32);
    float z[64];
#pragma unroll
    for (int c = 0; c < 32; ++c) z[c] = xb[c * DHW_];
#pragma unroll
    for (int q = 0; q < 8; ++q) {
        float4 m4 = mt[q];
        float a0 = m4.x - z[4*q],   a1 = m4.y - z[4*q+1];
        float a2 = m4.z - z[4*q+2], a3 = m4.w - z[4*q+3];
        z[32+4*q]   = a0 > 0.f ? a0 : 0.f;
        z[32+4*q+1] = a1 > 0.f ? a1 : 0.f;
        z[32+4*q+2] = a2 > 0.f ? a2 : 0.f;
        z[32+4*q+3] = a3 > 0.f ? a3 : 0.f;
    }
    __shared__ float ytile[256][33];
    float* yout = y + (size_t)b * CDHW_ + p;        // [b][o][p], OC==C
    for (int o = 0; o < 32; ++o) {
        float a = bias[o];
#pragma unroll
        for (int c = 0; c < 64; ++c) a = fmaf(w[o * 64 + c], z[c], a);
        yout[o * DHW_] = a;
        ytile[threadIdx.x][o] = a;
    }
    __syncthreads();
    int o = threadIdx.x & 31, seg = threadIdx.x >> 5;
    float ps = 0.f, pq = 0.f;
#pragma unroll
    for (int j = 0; j < 32; ++j) {
        float v = ytile[seg * 32 + j][o];
        ps += v; pq += v * v;
    }
    __shared__ float psum[8][32], psq[8][32];
    psum[seg][o] = ps; psq[seg][o] = pq;
    __syncthreads();
    if (threadIdx.x < 32) {
        double ts = 0.0, tq = 0.0;
#pragma unroll
        for (int s2 = 0; s2 < 8; ++s2) { ts += (double)psum[s2][threadIdx.x]; tq += (double)psq[s2][threadIdx.x]; }
        atomicAdd(&acc[4 + threadIdx.x], ts);
        atomicAdd(&acc[36 + threadIdx.x], tq);
    }
}

// ---------------- BN normalize (training stats, biased var) + exact GELU, in-place ----------------
__global__ __launch_bounds__(256) void k_out(float* __restrict__ y, const double* __restrict__ acc,
                                             const float* __restrict__ gamma, const float* __restrict__ beta) {
    int idx = blockIdx.x * 256 + threadIdx.x;       // over 1,048,576 float4
    int elem = idx << 2;
    int o = (elem >> 16) & 31;
    double mu = acc[4 + o] / (double)BN_N_;
    double var = acc[36 + o] / (double)BN_N_ - mu * mu;
    float rstd = (float)(1.0 / sqrt(var + 1e-5));
    float mu_f = (float)mu;
    float g = gamma[o], be = beta[o];
    float4 v = ((const float4*)y)[idx];
    float* vv = (float*)&v;
#pragma unroll
    for (int j = 0; j < 4; ++j) {
        float t = (vv[j] - mu_f) * rstd * g + be;
        vv[j] = 0.5f * t * (1.f + erff(t * 0.70710678118654752f));
    }
    ((float4*)y)[idx] = v;
}

extern "C" void kernel_launch(void* const* d_in, const int* in_sizes, int n_in,
                              void* d_out, int out_size, void* d_ws, size_t ws_size,
                              hipStream_t stream) {
    const float* x     = (const float*)d_in[0];
    const float* w     = (const float*)d_in[1];
    const float* bias  = (const float*)d_in[2];
    const float* gamma = (const float*)d_in[3];
    const float* beta  = (const float*)d_in[4];
    float* out = (float*)d_out;
    float* MT  = (float*)d_ws;                       // transposed [b][p][c]
    double* acc = (double*)((char*)d_ws + ACC_OFF);

    hipMemsetAsync(acc, 0, 68 * sizeof(double), stream);     // zero f64 accumulators every call
    k_norm  <<<512, 256, 0, stream>>>(x, acc);
    k_pass_w<<<512, 256, 0, stream>>>(x, acc, MT);
    k_ring16<W_,  HW_><<<dim3(8, 32, 2), 256, 0, stream>>>(x, acc, MT);   // H pass (F = d)
    k_ring16<HW_, W_ ><<<dim3(8, 32, 2), 256, 0, stream>>>(x, acc, MT);   // D pass (F = h)
    k_conv  <<<512, 256, 0, stream>>>(x, MT, w, bias, out, acc);
    k_out   <<<4096, 256, 0, stream>>>(out, acc, gamma, beta);
}